// Round 11
// baseline (603.098 us; speedup 1.0000x reference)
//
#include <hip/hip_runtime.h>
#include <hip/hip_bf16.h>
#include <hip/hip_cooperative_groups.h>
namespace cg = cooperative_groups;

#define NN 50000
#define NE 600000
#define BAG 16
#define EMB 128
#define HID 128
#define NC 10
#define NG 512
#define PAD_IDX 1
#define VOCAB 10000
#define SLOTS 64                  // fixed-width CSR row; P(deg>64 | lam=12) ~ 1e-30
#define TPAIRS (VOCAB * EMB / 2)  // 640k bf16 pairs in the table
#define WPAIRS (4 * HID * EMB / 2)
#define NE4 (NE / 4)              // 150000 edge-quads
#define GRID 256
#define BLK 256
#define NTILES ((NN + 127) / 128)  // 391 sage tiles
#define AGVB (NN / 4)              // 12500 aggr vblocks (4 nodes each, exact)
#define EMVB (NN / 16)             // 3125 embed vblocks (16 nodes each, exact)
#define PLVB ((NTILES + 1) / 2)    // 196 pool vblocks (2 chunks each)
#define SCBLK ((NE4 + 255) / 256)  // fallback scatter blocks

typedef __attribute__((ext_vector_type(8))) short v8s;
typedef __attribute__((ext_vector_type(4))) float v4f;

__device__ __forceinline__ float bflo(unsigned u) { return __uint_as_float(u << 16); }
__device__ __forceinline__ float bfhi(unsigned u) { return __uint_as_float(u & 0xffff0000u); }
__device__ __forceinline__ unsigned short f2bf(float f) {
    unsigned u = __float_as_uint(f);
    return (unsigned short)((u + 0x7fffu + ((u >> 16) & 1u)) >> 16);
}
__device__ __forceinline__ void acc8(float* a, v8s v) {
    unsigned* u = (unsigned*)&v;
#pragma unroll
    for (int j = 0; j < 4; j++) {
        a[2 * j] += bflo(u[j]);
        a[2 * j + 1] += bfhi(u[j]);
    }
}

// ======================= shared phase bodies (device) =======================

__device__ __forceinline__ void conv_body(int i, const float* __restrict__ t,
                                          unsigned short* __restrict__ tb,
                                          const float* __restrict__ w1l,
                                          const float* __restrict__ w1r,
                                          const float* __restrict__ w2l,
                                          const float* __restrict__ w2r,
                                          unsigned short* __restrict__ wbf,
                                          int* __restrict__ cnt, float* __restrict__ gsum,
                                          float* __restrict__ gcnt) {
    if (i < NN) cnt[i] = 0;
    if (i < NG * HID) gsum[i] = 0.f;
    if (i < NG) gcnt[i] = 0.f;
    if (i < TPAIRS) {
        float2 v = *(const float2*)(t + (size_t)i * 2);
        unsigned lo = f2bf(v.x), hi = f2bf(v.y);
        *(unsigned*)(tb + (size_t)i * 2) = lo | (hi << 16);
    } else if (i < TPAIRS + WPAIRS) {
        int j = i - TPAIRS;
        int k = j * 2;
        int arr = k >> 14;
        int o = k & 16383;
        const float* w = (arr == 0) ? w1l : (arr == 1) ? w1r : (arr == 2) ? w2l : w2r;
        float2 v = *(const float2*)(w + o);
        unsigned lo = f2bf(v.x), hi = f2bf(v.y);
        *(unsigned*)(wbf + k) = lo | (hi << 16);
    }
}

__device__ __forceinline__ void scatter_body(int t, const int* __restrict__ src,
                                             const int* __restrict__ dst,
                                             int* __restrict__ cnt,
                                             int* __restrict__ slots) {
    int4 s = *((const int4*)src + t);
    int4 d = *((const int4*)dst + t);
    int p0 = atomicAdd(&cnt[d.x], 1);
    int p1 = atomicAdd(&cnt[d.y], 1);
    int p2 = atomicAdd(&cnt[d.z], 1);
    int p3 = atomicAdd(&cnt[d.w], 1);
    if (p0 < SLOTS) slots[(size_t)d.x * SLOTS + p0] = s.x;
    if (p1 < SLOTS) slots[(size_t)d.y * SLOTS + p1] = s.y;
    if (p2 < SLOTS) slots[(size_t)d.z * SLOTS + p2] = s.z;
    if (p3 < SLOTS) slots[(size_t)d.w * SLOTS + p3] = s.w;
}

// embed: one 16-lane group per node; PAD row of table is exactly zero
__device__ __forceinline__ void embed_body(int node, int sl, const int* __restrict__ tokens,
                                           const unsigned short* __restrict__ table,
                                           unsigned short* __restrict__ x0) {
    const int* tp = tokens + node * BAG;
    float a[8];
#pragma unroll
    for (int j = 0; j < 8; j++) a[j] = 0.f;
    int c = 0;
#pragma unroll
    for (int t = 0; t < BAG; t++) {
        int tok = tp[t];  // group-uniform broadcast load
        c += (tok != PAD_IDX);
        v8s v = *(const v8s*)(table + (size_t)tok * EMB + sl * 8);
        acc8(a, v);
    }
    float inv = 1.0f / (float)(c > 0 ? c : 1);
    uint4 o;
    o.x = f2bf(a[0] * inv) | ((unsigned)f2bf(a[1] * inv) << 16);
    o.y = f2bf(a[2] * inv) | ((unsigned)f2bf(a[3] * inv) << 16);
    o.z = f2bf(a[4] * inv) | ((unsigned)f2bf(a[5] * inv) << 16);
    o.w = f2bf(a[6] * inv) | ((unsigned)f2bf(a[7] * inv) << 16);
    *(uint4*)(x0 + (size_t)node * EMB + sl * 8) = o;
}

// aggr: one wave per node, slot-CSR, indices in one lane-parallel load
__device__ __forceinline__ void aggr_body(int node, int lane,
                                          const unsigned short* __restrict__ x,
                                          const int* __restrict__ cnt,
                                          const int* __restrict__ slots,
                                          unsigned short* __restrict__ aggr) {
    int deg = cnt[node];
    int m = deg > SLOTS ? SLOTS : deg;
    int g = lane >> 4, sl = lane & 15;
    float a[8];
#pragma unroll
    for (int j = 0; j < 8; j++) a[j] = 0.f;
    int idx_l = slots[(size_t)node * SLOTS + ((lane < m) ? lane : 0)];
    int i = 0;
    for (; i + 8 <= m; i += 8) {
        int t0 = __shfl(idx_l, i + g, 64);
        int t1 = __shfl(idx_l, i + 4 + g, 64);
        v8s v0 = *(const v8s*)(x + (size_t)t0 * HID + sl * 8);
        v8s v1 = *(const v8s*)(x + (size_t)t1 * HID + sl * 8);
        acc8(a, v0);
        acc8(a, v1);
    }
    for (; i + 4 <= m; i += 4) {
        int t0 = __shfl(idx_l, i + g, 64);
        v8s v0 = *(const v8s*)(x + (size_t)t0 * HID + sl * 8);
        acc8(a, v0);
    }
    int rem = m - i;
    if (rem > 0) {
        int t0 = __shfl(idx_l, (g < rem) ? i + g : i, 64);
        v8s v0 = *(const v8s*)(x + (size_t)t0 * HID + sl * 8);
        if (g < rem) acc8(a, v0);
    }
#pragma unroll
    for (int j = 0; j < 8; j++) {
        a[j] += __shfl_xor(a[j], 16, 64);
        a[j] += __shfl_xor(a[j], 32, 64);
    }
    float inv = 1.0f / (float)(deg > 0 ? deg : 1);
    if (g == 0) {
        uint4 o;
        o.x = f2bf(a[0] * inv) | ((unsigned)f2bf(a[1] * inv) << 16);
        o.y = f2bf(a[2] * inv) | ((unsigned)f2bf(a[3] * inv) << 16);
        o.z = f2bf(a[4] * inv) | ((unsigned)f2bf(a[5] * inv) << 16);
        o.w = f2bf(a[6] * inv) | ((unsigned)f2bf(a[7] * inv) << 16);
        *(uint4*)(aggr + (size_t)node * HID + sl * 8) = o;
    }
}

// sage tile (256 threads): relu(aggr@wl^T + b + x@wr^T) for rows [row0,row0+128)
__device__ __forceinline__ void sage_tile(int row0, const unsigned short* __restrict__ xa,
                                          const unsigned short* __restrict__ xr,
                                          const unsigned short* __restrict__ wl,
                                          const unsigned short* __restrict__ wr,
                                          const float* __restrict__ bias,
                                          unsigned short* __restrict__ out,
                                          unsigned short* As, unsigned short* Bs) {
    int tid = threadIdx.x;
    int wave = tid >> 6, lane = tid & 63;
    int q = lane >> 4, l16 = lane & 15;
    v4f acc[2][8];
#pragma unroll
    for (int m = 0; m < 2; m++)
#pragma unroll
        for (int n = 0; n < 8; n++) acc[m][n] = (v4f){0.f, 0.f, 0.f, 0.f};
    for (int kc = 0; kc < 8; kc++) {
        const unsigned short* Ag = (kc < 4) ? xa : xr;
        const unsigned short* Bg = (kc < 4) ? wl : wr;
        int koff = (kc & 3) * 32;
#pragma unroll
        for (int it = 0; it < 2; it++) {
            int seg = tid + it * 256;
            int r = seg >> 2, sg = seg & 3;
            int gr = row0 + r;
            if (gr > NN - 1) gr = NN - 1;
            v8s a = *(const v8s*)(Ag + (size_t)gr * HID + koff + sg * 8);
            *(v8s*)(As + r * 32 + sg * 8) = a;
            v8s b = *(const v8s*)(Bg + (size_t)r * HID + koff + sg * 8);
            *(v8s*)(Bs + r * 32 + sg * 8) = b;
        }
        __syncthreads();
        v8s a0 = *(const v8s*)(As + (wave * 32 + l16) * 32 + q * 8);
        v8s a1 = *(const v8s*)(As + (wave * 32 + 16 + l16) * 32 + q * 8);
#pragma unroll
        for (int nt = 0; nt < 8; nt++) {
            v8s b = *(const v8s*)(Bs + (nt * 16 + l16) * 32 + q * 8);
            acc[0][nt] = __builtin_amdgcn_mfma_f32_16x16x32_bf16(a0, b, acc[0][nt], 0, 0, 0);
            acc[1][nt] = __builtin_amdgcn_mfma_f32_16x16x32_bf16(a1, b, acc[1][nt], 0, 0, 0);
        }
        __syncthreads();
    }
#pragma unroll
    for (int nt = 0; nt < 8; nt++) {
        int col = nt * 16 + l16;
        float bv = bias[col];
#pragma unroll
        for (int mt = 0; mt < 2; mt++) {
#pragma unroll
            for (int r = 0; r < 4; r++) {
                int row = row0 + wave * 32 + mt * 16 + q * 4 + r;
                if (row < NN) {
                    float v = acc[mt][nt][r] + bv;
                    v = v > 0.f ? v : 0.f;
                    out[(size_t)row * HID + col] = f2bf(v);
                }
            }
        }
    }
}

// pool chunk: 128 sorted nodes, run-length accumulate, few atomics
__device__ __forceinline__ void pool_chunk(int chunk, int col,
                                           const unsigned short* __restrict__ x2,
                                           const int* __restrict__ batch,
                                           float* __restrict__ gsum,
                                           float* __restrict__ gcnt) {
    int start = chunk * 128;
    int end = start + 128;
    if (end > NN) end = NN;
    int cur = batch[start];
    float acc = 0.f;
    int c = 0;
    for (int n = start; n < end; n++) {
        int b = batch[n];
        if (b != cur) {
            atomicAdd(&gsum[cur * HID + col], acc);
            if (col == 0) atomicAdd(&gcnt[cur], (float)c);
            acc = 0.f;
            c = 0;
            cur = b;
        }
        acc += __uint_as_float(((unsigned)x2[(size_t)n * HID + col]) << 16);
        c++;
    }
    atomicAdd(&gsum[cur * HID + col], acc);
    if (col == 0) atomicAdd(&gcnt[cur], (float)c);
}

// ======================= cooperative mega-kernel =======================
__global__ void k_mega(const int* __restrict__ tokens, const int* __restrict__ src,
                       const int* __restrict__ dst, const int* __restrict__ batch,
                       const float* __restrict__ emb_table, const float* __restrict__ w1l,
                       const float* __restrict__ b1, const float* __restrict__ w1r,
                       const float* __restrict__ w2l, const float* __restrict__ b2,
                       const float* __restrict__ w2r, const float* __restrict__ w_out,
                       const float* __restrict__ b_out, float* __restrict__ out,
                       int* __restrict__ cnt, int* __restrict__ slots,
                       unsigned short* __restrict__ wbf, float* __restrict__ gsum,
                       float* __restrict__ gcnt, unsigned short* __restrict__ table_bf,
                       unsigned short* __restrict__ x0, unsigned short* __restrict__ x1,
                       unsigned short* __restrict__ aggr) {
    __shared__ unsigned short As[128 * 32];
    __shared__ unsigned short Bs[128 * 32];
    cg::grid_group grid = cg::this_grid();
    const int tid = threadIdx.x;
    const int gi = blockIdx.x * BLK + tid;
    const int gstride = GRID * BLK;  // 65536

    // P0: zero + convert
    for (int i = gi; i < TPAIRS + WPAIRS; i += gstride)
        conv_body(i, emb_table, table_bf, w1l, w1r, w2l, w2r, wbf, cnt, gsum, gcnt);
    grid.sync();

    // P1: scatter + embed
    for (int t = gi; t < NE4; t += gstride) scatter_body(t, src, dst, cnt, slots);
    {
        int sl = tid & 15;
        for (int vb = blockIdx.x; vb < EMVB; vb += GRID)
            embed_body(vb * 16 + (tid >> 4), sl, tokens, table_bf, x0);
    }
    grid.sync();

    // P2..P5: two SAGE layers
    {
        int lane = tid & 63;
        for (int vb = blockIdx.x; vb < AGVB; vb += GRID)
            aggr_body(vb * 4 + (tid >> 6), lane, x0, cnt, slots, aggr);
    }
    grid.sync();
    for (int vt = blockIdx.x; vt < NTILES; vt += GRID)
        sage_tile(vt * 128, aggr, x0, wbf, wbf + 16384, b1, x1, As, Bs);
    grid.sync();
    {
        int lane = tid & 63;
        for (int vb = blockIdx.x; vb < AGVB; vb += GRID)
            aggr_body(vb * 4 + (tid >> 6), lane, x1, cnt, slots, aggr);
    }
    grid.sync();
    for (int vt = blockIdx.x; vt < NTILES; vt += GRID)
        sage_tile(vt * 128, aggr, x1, wbf + 32768, wbf + 49152, b2, x0, As, Bs);
    grid.sync();

    // P6: pool
    for (int vb = blockIdx.x; vb < PLVB; vb += GRID) {
        int chunk = vb * 2 + (tid >> 7);
        if (chunk < NTILES) pool_chunk(chunk, tid & 127, x0, batch, gsum, gcnt);
    }
    grid.sync();

    // P7: classifier
    float* mean = (float*)As;
    for (int g = blockIdx.x; g < NG; g += GRID) {
        if (tid < HID) mean[tid] = gsum[g * HID + tid] / fmaxf(gcnt[g], 1.0f);
        __syncthreads();
        if (tid < NC) {
            float s = b_out[tid];
#pragma unroll 16
            for (int d = 0; d < HID; d++) s += mean[d] * w_out[tid * HID + d];
            out[g * NC + tid] = s;
        }
        __syncthreads();
    }
}

// ======================= fallback kernels (R9 structure) =======================
__global__ void k_conv(const float* __restrict__ t, unsigned short* __restrict__ tb,
                       const float* __restrict__ w1l, const float* __restrict__ w1r,
                       const float* __restrict__ w2l, const float* __restrict__ w2r,
                       unsigned short* __restrict__ wbf, int* __restrict__ cnt,
                       float* __restrict__ gsum, float* __restrict__ gcnt) {
    int i = blockIdx.x * blockDim.x + threadIdx.x;
    conv_body(i, t, tb, w1l, w1r, w2l, w2r, wbf, cnt, gsum, gcnt);
}

__global__ __launch_bounds__(256) void k_scatem(const int* __restrict__ src,
                                                const int* __restrict__ dst,
                                                int* __restrict__ cnt,
                                                int* __restrict__ slots,
                                                const int* __restrict__ tokens,
                                                const unsigned short* __restrict__ table,
                                                unsigned short* __restrict__ x0) {
    int b = blockIdx.x;
    if (b < SCBLK) {
        int t = b * 256 + threadIdx.x;
        if (t < NE4) scatter_body(t, src, dst, cnt, slots);
        return;
    }
    b -= SCBLK;
    embed_body(b * 16 + (threadIdx.x >> 4), threadIdx.x & 15, tokens, table, x0);
}

__global__ __launch_bounds__(256) void k_aggr(const unsigned short* __restrict__ x,
                                              const int* __restrict__ cnt,
                                              const int* __restrict__ slots,
                                              unsigned short* __restrict__ aggr) {
    int node = blockIdx.x * 4 + (threadIdx.x >> 6);
    if (node >= NN) return;
    aggr_body(node, threadIdx.x & 63, x, cnt, slots, aggr);
}

__global__ __launch_bounds__(256) void k_sage(const unsigned short* __restrict__ xa,
                                              const unsigned short* __restrict__ xr,
                                              const unsigned short* __restrict__ wl,
                                              const unsigned short* __restrict__ wr,
                                              const float* __restrict__ bias,
                                              unsigned short* __restrict__ out) {
    __shared__ unsigned short As[128 * 32];
    __shared__ unsigned short Bs[128 * 32];
    sage_tile(blockIdx.x * 128, xa, xr, wl, wr, bias, out, As, Bs);
}

__global__ __launch_bounds__(128) void k_pool(const unsigned short* __restrict__ x2,
                                              const int* __restrict__ batch,
                                              float* __restrict__ gsum,
                                              float* __restrict__ gcnt) {
    pool_chunk(blockIdx.x, threadIdx.x, x2, batch, gsum, gcnt);
}

__global__ __launch_bounds__(128) void k_final(const float* __restrict__ gsum,
                                               const float* __restrict__ gcnt,
                                               const float* __restrict__ w_out,
                                               const float* __restrict__ b_out,
                                               float* __restrict__ out) {
    __shared__ float mean[HID];
    int g = blockIdx.x, tid = threadIdx.x;
    mean[tid] = gsum[g * HID + tid] / fmaxf(gcnt[g], 1.0f);
    __syncthreads();
    if (tid < NC) {
        float s = b_out[tid];
#pragma unroll 16
        for (int d = 0; d < HID; d++) s += mean[d] * w_out[tid * HID + d];
        out[g * NC + tid] = s;
    }
}

extern "C" void kernel_launch(void* const* d_in, const int* in_sizes, int n_in,
                              void* d_out, int out_size, void* d_ws, size_t ws_size,
                              hipStream_t stream) {
    const int* x_tokens = (const int*)d_in[0];
    const int* edge = (const int*)d_in[1];
    const int* batch = (const int*)d_in[2];
    const float* emb_table = (const float*)d_in[3];
    const float* w1l = (const float*)d_in[4];
    const float* b1 = (const float*)d_in[5];
    const float* w1r = (const float*)d_in[6];
    const float* w2l = (const float*)d_in[7];
    const float* b2 = (const float*)d_in[8];
    const float* w2r = (const float*)d_in[9];
    const float* w_out = (const float*)d_in[10];
    const float* b_out = (const float*)d_in[11];
    float* out = (float*)d_out;

    char* ws = (char*)d_ws;
    size_t off = 0;
    auto alloc = [&](size_t bytes) {
        void* p = ws + off;
        off += (bytes + 255) & ~(size_t)255;
        return p;
    };
    int* cnt = (int*)alloc(NN * 4);
    int* slots = (int*)alloc((size_t)NN * SLOTS * 4);  // fixed-width CSR, 12.8 MB
    unsigned short* wbf = (unsigned short*)alloc(4 * HID * EMB * 2);
    float* gsum = (float*)alloc(NG * HID * 4);
    float* gcnt = (float*)alloc(NG * 4);
    unsigned short* x0 = (unsigned short*)alloc((size_t)NN * EMB * 2);
    unsigned short* x1 = (unsigned short*)alloc((size_t)NN * HID * 2);
    unsigned short* aggrb = (unsigned short*)alloc((size_t)NN * HID * 2);
    unsigned short* table_bf = x1;  // x1 dead until sage1 writes it; reuse

    const int* srcp = edge;
    const int* dstp = edge + NE;

    void* args[] = {(void*)&x_tokens,  (void*)&srcp, (void*)&dstp, (void*)&batch,
                    (void*)&emb_table, (void*)&w1l,  (void*)&b1,   (void*)&w1r,
                    (void*)&w2l,       (void*)&b2,   (void*)&w2r,  (void*)&w_out,
                    (void*)&b_out,     (void*)&out,  (void*)&cnt,  (void*)&slots,
                    (void*)&wbf,       (void*)&gsum, (void*)&gcnt, (void*)&table_bf,
                    (void*)&x0,        (void*)&x1,   (void*)&aggrb};
    hipError_t err = hipLaunchCooperativeKernel((void*)k_mega, dim3(GRID), dim3(BLK),
                                                args, 0, stream);
    if (err != hipSuccess) {
        // fallback: same phases as discrete kernels (R9-proven path)
        k_conv<<<(TPAIRS + WPAIRS + 255) / 256, 256, 0, stream>>>(
            emb_table, table_bf, w1l, w1r, w2l, w2r, wbf, cnt, gsum, gcnt);
        k_scatem<<<SCBLK + EMVB, 256, 0, stream>>>(srcp, dstp, cnt, slots, x_tokens,
                                                   table_bf, x0);
        k_aggr<<<(NN + 3) / 4, 256, 0, stream>>>(x0, cnt, slots, aggrb);
        k_sage<<<NTILES, 256, 0, stream>>>(aggrb, x0, wbf, wbf + 16384, b1, x1);
        k_aggr<<<(NN + 3) / 4, 256, 0, stream>>>(x1, cnt, slots, aggrb);
        k_sage<<<NTILES, 256, 0, stream>>>(aggrb, x1, wbf + 32768, wbf + 49152, b2, x0);
        k_pool<<<NTILES, 128, 0, stream>>>(x0, batch, gsum, gcnt);
        k_final<<<NG, 128, 0, stream>>>(gsum, gcnt, w_out, b_out, out);
    }
}

// Round 12
// 595.877 us; speedup vs baseline: 1.0121x; 1.0121x over previous
//
#include <hip/hip_runtime.h>
#include <hip/hip_bf16.h>
#include <hip/hip_cooperative_groups.h>
namespace cg = cooperative_groups;

#define NN 50000
#define NE 600000
#define BAG 16
#define EMB 128
#define HID 128
#define NC 10
#define NG 512
#define PAD_IDX 1
#define VOCAB 10000
#define SLOTS 64                  // fixed-width CSR row; P(deg>64 | lam=12) ~ 1e-30
#define TPAIRS (VOCAB * EMB / 2)  // 640k bf16 pairs in the table
#define WPAIRS (4 * HID * EMB / 2)
#define NE4 (NE / 4)              // 150000 edge-quads
#define BLK 256
#define NTILES ((NN + 127) / 128)  // 391 sage tiles
#define AGVB (NN / 4)              // 12500 aggr vblocks (4 nodes each, exact)
#define EMVB (NN / 16)             // 3125 embed vblocks (16 nodes each, exact)
#define PLVB ((NTILES + 1) / 2)    // 196 pool vblocks (2 chunks each)
#define SCBLK ((NE4 + 255) / 256)  // fallback scatter blocks

typedef __attribute__((ext_vector_type(8))) short v8s;
typedef __attribute__((ext_vector_type(4))) float v4f;

__device__ __forceinline__ float bflo(unsigned u) { return __uint_as_float(u << 16); }
__device__ __forceinline__ float bfhi(unsigned u) { return __uint_as_float(u & 0xffff0000u); }
__device__ __forceinline__ unsigned short f2bf(float f) {
    unsigned u = __float_as_uint(f);
    return (unsigned short)((u + 0x7fffu + ((u >> 16) & 1u)) >> 16);
}
__device__ __forceinline__ void acc8(float* a, v8s v) {
    unsigned* u = (unsigned*)&v;
#pragma unroll
    for (int j = 0; j < 4; j++) {
        a[2 * j] += bflo(u[j]);
        a[2 * j + 1] += bfhi(u[j]);
    }
}

// ======================= shared phase bodies (device) =======================

__device__ __forceinline__ void conv_body(int i, const float* __restrict__ t,
                                          unsigned short* __restrict__ tb,
                                          const float* __restrict__ w1l,
                                          const float* __restrict__ w1r,
                                          const float* __restrict__ w2l,
                                          const float* __restrict__ w2r,
                                          unsigned short* __restrict__ wbf,
                                          int* __restrict__ cnt, float* __restrict__ gsum,
                                          float* __restrict__ gcnt) {
    if (i < NN) cnt[i] = 0;
    if (i < NG * HID) gsum[i] = 0.f;
    if (i < NG) gcnt[i] = 0.f;
    if (i < TPAIRS) {
        float2 v = *(const float2*)(t + (size_t)i * 2);
        unsigned lo = f2bf(v.x), hi = f2bf(v.y);
        *(unsigned*)(tb + (size_t)i * 2) = lo | (hi << 16);
    } else if (i < TPAIRS + WPAIRS) {
        int j = i - TPAIRS;
        int k = j * 2;
        int arr = k >> 14;
        int o = k & 16383;
        const float* w = (arr == 0) ? w1l : (arr == 1) ? w1r : (arr == 2) ? w2l : w2r;
        float2 v = *(const float2*)(w + o);
        unsigned lo = f2bf(v.x), hi = f2bf(v.y);
        *(unsigned*)(wbf + k) = lo | (hi << 16);
    }
}

__device__ __forceinline__ void scatter_body(int t, const int* __restrict__ src,
                                             const int* __restrict__ dst,
                                             int* __restrict__ cnt,
                                             int* __restrict__ slots) {
    int4 s = *((const int4*)src + t);
    int4 d = *((const int4*)dst + t);
    int p0 = atomicAdd(&cnt[d.x], 1);
    int p1 = atomicAdd(&cnt[d.y], 1);
    int p2 = atomicAdd(&cnt[d.z], 1);
    int p3 = atomicAdd(&cnt[d.w], 1);
    if (p0 < SLOTS) slots[(size_t)d.x * SLOTS + p0] = s.x;
    if (p1 < SLOTS) slots[(size_t)d.y * SLOTS + p1] = s.y;
    if (p2 < SLOTS) slots[(size_t)d.z * SLOTS + p2] = s.z;
    if (p3 < SLOTS) slots[(size_t)d.w * SLOTS + p3] = s.w;
}

// embed: one 16-lane group per node; PAD row of table is exactly zero
__device__ __forceinline__ void embed_body(int node, int sl, const int* __restrict__ tokens,
                                           const unsigned short* __restrict__ table,
                                           unsigned short* __restrict__ x0) {
    const int* tp = tokens + node * BAG;
    float a[8];
#pragma unroll
    for (int j = 0; j < 8; j++) a[j] = 0.f;
    int c = 0;
#pragma unroll
    for (int t = 0; t < BAG; t++) {
        int tok = tp[t];  // group-uniform broadcast load
        c += (tok != PAD_IDX);
        v8s v = *(const v8s*)(table + (size_t)tok * EMB + sl * 8);
        acc8(a, v);
    }
    float inv = 1.0f / (float)(c > 0 ? c : 1);
    uint4 o;
    o.x = f2bf(a[0] * inv) | ((unsigned)f2bf(a[1] * inv) << 16);
    o.y = f2bf(a[2] * inv) | ((unsigned)f2bf(a[3] * inv) << 16);
    o.z = f2bf(a[4] * inv) | ((unsigned)f2bf(a[5] * inv) << 16);
    o.w = f2bf(a[6] * inv) | ((unsigned)f2bf(a[7] * inv) << 16);
    *(uint4*)(x0 + (size_t)node * EMB + sl * 8) = o;
}

// aggr: one wave per node, slot-CSR, indices in one lane-parallel load
__device__ __forceinline__ void aggr_body(int node, int lane,
                                          const unsigned short* __restrict__ x,
                                          const int* __restrict__ cnt,
                                          const int* __restrict__ slots,
                                          unsigned short* __restrict__ aggr) {
    int deg = cnt[node];
    int m = deg > SLOTS ? SLOTS : deg;
    int g = lane >> 4, sl = lane & 15;
    float a[8];
#pragma unroll
    for (int j = 0; j < 8; j++) a[j] = 0.f;
    int idx_l = slots[(size_t)node * SLOTS + ((lane < m) ? lane : 0)];
    int i = 0;
    for (; i + 8 <= m; i += 8) {
        int t0 = __shfl(idx_l, i + g, 64);
        int t1 = __shfl(idx_l, i + 4 + g, 64);
        v8s v0 = *(const v8s*)(x + (size_t)t0 * HID + sl * 8);
        v8s v1 = *(const v8s*)(x + (size_t)t1 * HID + sl * 8);
        acc8(a, v0);
        acc8(a, v1);
    }
    for (; i + 4 <= m; i += 4) {
        int t0 = __shfl(idx_l, i + g, 64);
        v8s v0 = *(const v8s*)(x + (size_t)t0 * HID + sl * 8);
        acc8(a, v0);
    }
    int rem = m - i;
    if (rem > 0) {
        int t0 = __shfl(idx_l, (g < rem) ? i + g : i, 64);
        v8s v0 = *(const v8s*)(x + (size_t)t0 * HID + sl * 8);
        if (g < rem) acc8(a, v0);
    }
#pragma unroll
    for (int j = 0; j < 8; j++) {
        a[j] += __shfl_xor(a[j], 16, 64);
        a[j] += __shfl_xor(a[j], 32, 64);
    }
    float inv = 1.0f / (float)(deg > 0 ? deg : 1);
    if (g == 0) {
        uint4 o;
        o.x = f2bf(a[0] * inv) | ((unsigned)f2bf(a[1] * inv) << 16);
        o.y = f2bf(a[2] * inv) | ((unsigned)f2bf(a[3] * inv) << 16);
        o.z = f2bf(a[4] * inv) | ((unsigned)f2bf(a[5] * inv) << 16);
        o.w = f2bf(a[6] * inv) | ((unsigned)f2bf(a[7] * inv) << 16);
        *(uint4*)(aggr + (size_t)node * HID + sl * 8) = o;
    }
}

// sage tile (256 threads): relu(aggr@wl^T + b + x@wr^T) for rows [row0,row0+128)
__device__ __forceinline__ void sage_tile(int row0, const unsigned short* __restrict__ xa,
                                          const unsigned short* __restrict__ xr,
                                          const unsigned short* __restrict__ wl,
                                          const unsigned short* __restrict__ wr,
                                          const float* __restrict__ bias,
                                          unsigned short* __restrict__ out,
                                          unsigned short* As, unsigned short* Bs) {
    int tid = threadIdx.x;
    int wave = tid >> 6, lane = tid & 63;
    int q = lane >> 4, l16 = lane & 15;
    v4f acc[2][8];
#pragma unroll
    for (int m = 0; m < 2; m++)
#pragma unroll
        for (int n = 0; n < 8; n++) acc[m][n] = (v4f){0.f, 0.f, 0.f, 0.f};
    for (int kc = 0; kc < 8; kc++) {
        const unsigned short* Ag = (kc < 4) ? xa : xr;
        const unsigned short* Bg = (kc < 4) ? wl : wr;
        int koff = (kc & 3) * 32;
#pragma unroll
        for (int it = 0; it < 2; it++) {
            int seg = tid + it * 256;
            int r = seg >> 2, sg = seg & 3;
            int gr = row0 + r;
            if (gr > NN - 1) gr = NN - 1;
            v8s a = *(const v8s*)(Ag + (size_t)gr * HID + koff + sg * 8);
            *(v8s*)(As + r * 32 + sg * 8) = a;
            v8s b = *(const v8s*)(Bg + (size_t)r * HID + koff + sg * 8);
            *(v8s*)(Bs + r * 32 + sg * 8) = b;
        }
        __syncthreads();
        v8s a0 = *(const v8s*)(As + (wave * 32 + l16) * 32 + q * 8);
        v8s a1 = *(const v8s*)(As + (wave * 32 + 16 + l16) * 32 + q * 8);
#pragma unroll
        for (int nt = 0; nt < 8; nt++) {
            v8s b = *(const v8s*)(Bs + (nt * 16 + l16) * 32 + q * 8);
            acc[0][nt] = __builtin_amdgcn_mfma_f32_16x16x32_bf16(a0, b, acc[0][nt], 0, 0, 0);
            acc[1][nt] = __builtin_amdgcn_mfma_f32_16x16x32_bf16(a1, b, acc[1][nt], 0, 0, 0);
        }
        __syncthreads();
    }
#pragma unroll
    for (int nt = 0; nt < 8; nt++) {
        int col = nt * 16 + l16;
        float bv = bias[col];
#pragma unroll
        for (int mt = 0; mt < 2; mt++) {
#pragma unroll
            for (int r = 0; r < 4; r++) {
                int row = row0 + wave * 32 + mt * 16 + q * 4 + r;
                if (row < NN) {
                    float v = acc[mt][nt][r] + bv;
                    v = v > 0.f ? v : 0.f;
                    out[(size_t)row * HID + col] = f2bf(v);
                }
            }
        }
    }
}

// pool chunk: 128 sorted nodes, run-length accumulate, few atomics
__device__ __forceinline__ void pool_chunk(int chunk, int col,
                                           const unsigned short* __restrict__ x2,
                                           const int* __restrict__ batch,
                                           float* __restrict__ gsum,
                                           float* __restrict__ gcnt) {
    int start = chunk * 128;
    int end = start + 128;
    if (end > NN) end = NN;
    int cur = batch[start];
    float acc = 0.f;
    int c = 0;
    for (int n = start; n < end; n++) {
        int b = batch[n];
        if (b != cur) {
            atomicAdd(&gsum[cur * HID + col], acc);
            if (col == 0) atomicAdd(&gcnt[cur], (float)c);
            acc = 0.f;
            c = 0;
            cur = b;
        }
        acc += __uint_as_float(((unsigned)x2[(size_t)n * HID + col]) << 16);
        c++;
    }
    atomicAdd(&gsum[cur * HID + col], acc);
    if (col == 0) atomicAdd(&gcnt[cur], (float)c);
}

// ======================= cooperative mega-kernel (grid-stride, any grid) ======
__global__ __launch_bounds__(256) void k_mega(
    const int* __restrict__ tokens, const int* __restrict__ src,
    const int* __restrict__ dst, const int* __restrict__ batch,
    const float* __restrict__ emb_table, const float* __restrict__ w1l,
    const float* __restrict__ b1, const float* __restrict__ w1r,
    const float* __restrict__ w2l, const float* __restrict__ b2,
    const float* __restrict__ w2r, const float* __restrict__ w_out,
    const float* __restrict__ b_out, float* __restrict__ out, int* __restrict__ cnt,
    int* __restrict__ slots, unsigned short* __restrict__ wbf,
    float* __restrict__ gsum, float* __restrict__ gcnt,
    unsigned short* __restrict__ table_bf, unsigned short* __restrict__ x0,
    unsigned short* __restrict__ x1, unsigned short* __restrict__ aggr) {
    __shared__ unsigned short As[128 * 32];
    __shared__ unsigned short Bs[128 * 32];
    cg::grid_group grid = cg::this_grid();
    const int tid = threadIdx.x;
    const int nblk = gridDim.x;
    const int gi = blockIdx.x * BLK + tid;
    const int gstride = nblk * BLK;

    // P0: zero + convert
    for (int i = gi; i < TPAIRS + WPAIRS; i += gstride)
        conv_body(i, emb_table, table_bf, w1l, w1r, w2l, w2r, wbf, cnt, gsum, gcnt);
    grid.sync();

    // P1: scatter + embed
    for (int t = gi; t < NE4; t += gstride) scatter_body(t, src, dst, cnt, slots);
    {
        int sl = tid & 15;
        for (int vb = blockIdx.x; vb < EMVB; vb += nblk)
            embed_body(vb * 16 + (tid >> 4), sl, tokens, table_bf, x0);
    }
    grid.sync();

    // P2..P5: two SAGE layers
    {
        int lane = tid & 63;
        for (int vb = blockIdx.x; vb < AGVB; vb += nblk)
            aggr_body(vb * 4 + (tid >> 6), lane, x0, cnt, slots, aggr);
    }
    grid.sync();
    for (int vt = blockIdx.x; vt < NTILES; vt += nblk)
        sage_tile(vt * 128, aggr, x0, wbf, wbf + 16384, b1, x1, As, Bs);
    grid.sync();
    {
        int lane = tid & 63;
        for (int vb = blockIdx.x; vb < AGVB; vb += nblk)
            aggr_body(vb * 4 + (tid >> 6), lane, x1, cnt, slots, aggr);
    }
    grid.sync();
    for (int vt = blockIdx.x; vt < NTILES; vt += nblk)
        sage_tile(vt * 128, aggr, x1, wbf + 32768, wbf + 49152, b2, x0, As, Bs);
    grid.sync();

    // P6: pool
    for (int vb = blockIdx.x; vb < PLVB; vb += nblk) {
        int chunk = vb * 2 + (tid >> 7);
        if (chunk < NTILES) pool_chunk(chunk, tid & 127, x0, batch, gsum, gcnt);
    }
    grid.sync();

    // P7: classifier
    float* mean = (float*)As;
    for (int g = blockIdx.x; g < NG; g += nblk) {
        if (tid < HID) mean[tid] = gsum[g * HID + tid] / fmaxf(gcnt[g], 1.0f);
        __syncthreads();
        if (tid < NC) {
            float s = b_out[tid];
#pragma unroll 16
            for (int d = 0; d < HID; d++) s += mean[d] * w_out[tid * HID + d];
            out[g * NC + tid] = s;
        }
        __syncthreads();
    }
}

// ======================= fallback kernels (R9 structure) =======================
__global__ void k_conv(const float* __restrict__ t, unsigned short* __restrict__ tb,
                       const float* __restrict__ w1l, const float* __restrict__ w1r,
                       const float* __restrict__ w2l, const float* __restrict__ w2r,
                       unsigned short* __restrict__ wbf, int* __restrict__ cnt,
                       float* __restrict__ gsum, float* __restrict__ gcnt) {
    int i = blockIdx.x * blockDim.x + threadIdx.x;
    conv_body(i, t, tb, w1l, w1r, w2l, w2r, wbf, cnt, gsum, gcnt);
}

__global__ __launch_bounds__(256) void k_scatem(const int* __restrict__ src,
                                                const int* __restrict__ dst,
                                                int* __restrict__ cnt,
                                                int* __restrict__ slots,
                                                const int* __restrict__ tokens,
                                                const unsigned short* __restrict__ table,
                                                unsigned short* __restrict__ x0) {
    int b = blockIdx.x;
    if (b < SCBLK) {
        int t = b * 256 + threadIdx.x;
        if (t < NE4) scatter_body(t, src, dst, cnt, slots);
        return;
    }
    b -= SCBLK;
    embed_body(b * 16 + (threadIdx.x >> 4), threadIdx.x & 15, tokens, table, x0);
}

__global__ __launch_bounds__(256) void k_aggr(const unsigned short* __restrict__ x,
                                              const int* __restrict__ cnt,
                                              const int* __restrict__ slots,
                                              unsigned short* __restrict__ aggr) {
    int node = blockIdx.x * 4 + (threadIdx.x >> 6);
    if (node >= NN) return;
    aggr_body(node, threadIdx.x & 63, x, cnt, slots, aggr);
}

__global__ __launch_bounds__(256) void k_sage(const unsigned short* __restrict__ xa,
                                              const unsigned short* __restrict__ xr,
                                              const unsigned short* __restrict__ wl,
                                              const unsigned short* __restrict__ wr,
                                              const float* __restrict__ bias,
                                              unsigned short* __restrict__ out) {
    __shared__ unsigned short As[128 * 32];
    __shared__ unsigned short Bs[128 * 32];
    sage_tile(blockIdx.x * 128, xa, xr, wl, wr, bias, out, As, Bs);
}

__global__ __launch_bounds__(128) void k_pool(const unsigned short* __restrict__ x2,
                                              const int* __restrict__ batch,
                                              float* __restrict__ gsum,
                                              float* __restrict__ gcnt) {
    pool_chunk(blockIdx.x, threadIdx.x, x2, batch, gsum, gcnt);
}

__global__ __launch_bounds__(128) void k_final(const float* __restrict__ gsum,
                                               const float* __restrict__ gcnt,
                                               const float* __restrict__ w_out,
                                               const float* __restrict__ b_out,
                                               float* __restrict__ out) {
    __shared__ float mean[HID];
    int g = blockIdx.x, tid = threadIdx.x;
    mean[tid] = gsum[g * HID + tid] / fmaxf(gcnt[g], 1.0f);
    __syncthreads();
    if (tid < NC) {
        float s = b_out[tid];
#pragma unroll 16
        for (int d = 0; d < HID; d++) s += mean[d] * w_out[tid * HID + d];
        out[g * NC + tid] = s;
    }
}

extern "C" void kernel_launch(void* const* d_in, const int* in_sizes, int n_in,
                              void* d_out, int out_size, void* d_ws, size_t ws_size,
                              hipStream_t stream) {
    const int* x_tokens = (const int*)d_in[0];
    const int* edge = (const int*)d_in[1];
    const int* batch = (const int*)d_in[2];
    const float* emb_table = (const float*)d_in[3];
    const float* w1l = (const float*)d_in[4];
    const float* b1 = (const float*)d_in[5];
    const float* w1r = (const float*)d_in[6];
    const float* w2l = (const float*)d_in[7];
    const float* b2 = (const float*)d_in[8];
    const float* w2r = (const float*)d_in[9];
    const float* w_out = (const float*)d_in[10];
    const float* b_out = (const float*)d_in[11];
    float* out = (float*)d_out;

    char* ws = (char*)d_ws;
    size_t off = 0;
    auto alloc = [&](size_t bytes) {
        void* p = ws + off;
        off += (bytes + 255) & ~(size_t)255;
        return p;
    };
    int* cnt = (int*)alloc(NN * 4);
    int* slots = (int*)alloc((size_t)NN * SLOTS * 4);  // fixed-width CSR, 12.8 MB
    unsigned short* wbf = (unsigned short*)alloc(4 * HID * EMB * 2);
    float* gsum = (float*)alloc(NG * HID * 4);
    float* gcnt = (float*)alloc(NG * 4);
    unsigned short* x0 = (unsigned short*)alloc((size_t)NN * EMB * 2);
    unsigned short* x1 = (unsigned short*)alloc((size_t)NN * HID * 2);
    unsigned short* aggrb = (unsigned short*)alloc((size_t)NN * HID * 2);
    unsigned short* table_bf = x1;  // x1 dead until sage1 writes it; reuse

    const int* srcp = edge;
    const int* dstp = edge + NE;

    // size the cooperative grid for full co-residency (capture-safe driver query)
    int maxBlkPerCU = 0;
    hipError_t qerr = hipOccupancyMaxActiveBlocksPerMultiprocessor(&maxBlkPerCU,
                                                                   k_mega, BLK, 0);
    int grid = maxBlkPerCU * 256;  // MI355X: 256 CUs
    if (grid > 2048) grid = 2048;

    hipError_t err = hipErrorUnknown;
    if (qerr == hipSuccess && grid >= 256) {
        void* args[] = {(void*)&x_tokens,  (void*)&srcp, (void*)&dstp, (void*)&batch,
                        (void*)&emb_table, (void*)&w1l,  (void*)&b1,   (void*)&w1r,
                        (void*)&w2l,       (void*)&b2,   (void*)&w2r,  (void*)&w_out,
                        (void*)&b_out,     (void*)&out,  (void*)&cnt,  (void*)&slots,
                        (void*)&wbf,       (void*)&gsum, (void*)&gcnt, (void*)&table_bf,
                        (void*)&x0,        (void*)&x1,   (void*)&aggrb};
        err = hipLaunchCooperativeKernel((void*)k_mega, dim3(grid), dim3(BLK), args, 0,
                                         stream);
    }
    if (err != hipSuccess) {
        // fallback: same phases as discrete kernels (R9-proven path)
        k_conv<<<(TPAIRS + WPAIRS + 255) / 256, 256, 0, stream>>>(
            emb_table, table_bf, w1l, w1r, w2l, w2r, wbf, cnt, gsum, gcnt);
        k_scatem<<<SCBLK + EMVB, 256, 0, stream>>>(srcp, dstp, cnt, slots, x_tokens,
                                                   table_bf, x0);
        k_aggr<<<(NN + 3) / 4, 256, 0, stream>>>(x0, cnt, slots, aggrb);
        k_sage<<<NTILES, 256, 0, stream>>>(aggrb, x0, wbf, wbf + 16384, b1, x1);
        k_aggr<<<(NN + 3) / 4, 256, 0, stream>>>(x1, cnt, slots, aggrb);
        k_sage<<<NTILES, 256, 0, stream>>>(aggrb, x1, wbf + 32768, wbf + 49152, b2, x0);
        k_pool<<<NTILES, 128, 0, stream>>>(x0, batch, gsum, gcnt);
        k_final<<<NG, 128, 0, stream>>>(gsum, gcnt, w_out, b_out, out);
    }
}

// Round 13
// 209.585 us; speedup vs baseline: 2.8776x; 2.8431x over previous
//
#include <hip/hip_runtime.h>
#include <hip/hip_bf16.h>

#define NN 50000
#define NE 600000
#define BAG 16
#define EMB 128
#define HID 128
#define NC 10
#define NG 512
#define PAD_IDX 1
#define VOCAB 10000
#define SLOTS 64                  // fixed-width CSR row; P(deg>64 | lam=12) ~ 1e-30
#define TPAIRS (VOCAB * EMB / 2)  // 640k bf16 pairs in the table
#define WPAIRS (4 * HID * EMB / 2)
#define NE8 (NE / 8)               // 75000 edge-octets
#define SC8BLK ((NE8 + 255) / 256) // 293 scatter blocks
#define EMVB (NN / 16)             // 3125 embed blocks (16 nodes each, exact)
#define NTILES ((NN + 127) / 128)  // 391 sage/pool tiles

typedef __attribute__((ext_vector_type(8))) short v8s;
typedef __attribute__((ext_vector_type(4))) float v4f;

__device__ __forceinline__ float bflo(unsigned u) { return __uint_as_float(u << 16); }
__device__ __forceinline__ float bfhi(unsigned u) { return __uint_as_float(u & 0xffff0000u); }
__device__ __forceinline__ unsigned short f2bf(float f) {
    unsigned u = __float_as_uint(f);
    return (unsigned short)((u + 0x7fffu + ((u >> 16) & 1u)) >> 16);
}
__device__ __forceinline__ void acc8(float* a, v8s v) {
    unsigned* u = (unsigned*)&v;
#pragma unroll
    for (int j = 0; j < 4; j++) {
        a[2 * j] += bflo(u[j]);
        a[2 * j + 1] += bfhi(u[j]);
    }
}

// ---------- fp32->bf16 conversion (table + weights) and workspace zeroing ----------
__global__ void k_conv(const float* __restrict__ t, unsigned short* __restrict__ tb,
                       const float* __restrict__ w1l, const float* __restrict__ w1r,
                       const float* __restrict__ w2l, const float* __restrict__ w2r,
                       unsigned short* __restrict__ wbf, int* __restrict__ cnt,
                       float* __restrict__ gsum, float* __restrict__ gcnt) {
    int i = blockIdx.x * blockDim.x + threadIdx.x;
    if (i < NN) cnt[i] = 0;
    if (i < NG * HID) gsum[i] = 0.f;
    if (i < NG) gcnt[i] = 0.f;
    if (i < TPAIRS) {
        float2 v = *(const float2*)(t + (size_t)i * 2);
        unsigned lo = f2bf(v.x), hi = f2bf(v.y);
        *(unsigned*)(tb + (size_t)i * 2) = lo | (hi << 16);
    } else if (i < TPAIRS + WPAIRS) {
        int j = i - TPAIRS;
        int k = j * 2;      // element index in concatenated [w1l|w1r|w2l|w2r]
        int arr = k >> 14;  // 16384 elements per matrix
        int o = k & 16383;
        const float* w = (arr == 0) ? w1l : (arr == 1) ? w1r : (arr == 2) ? w2l : w2r;
        float2 v = *(const float2*)(w + o);
        unsigned lo = f2bf(v.x), hi = f2bf(v.y);
        *(unsigned*)(wbf + k) = lo | (hi << 16);
    }
}

// ---------- fused: embedding-bag mean (blocks 0..EMVB) + slot-CSR scatter ----------
// Embed first: the latency-bound long pole starts immediately; scatter back-fills.
// Embed: one 16-lane group per node, 16 independent row-gathers/wave in flight,
// no cross-lane reduction. PAD row of the table is exactly zero -> unconditional sum.
// Scatter: 8 edges/thread -> 8 independent atomics + 8 stores in flight per lane.
__global__ __launch_bounds__(256) void k_scatem(const int* __restrict__ src,
                                                const int* __restrict__ dst,
                                                int* __restrict__ cnt,
                                                int* __restrict__ slots,
                                                const int* __restrict__ tokens,
                                                const unsigned short* __restrict__ table,
                                                unsigned short* __restrict__ x0) {
    int b = blockIdx.x;
    if (b < EMVB) {
        int sl = threadIdx.x & 15;
        int node = b * 16 + (threadIdx.x >> 4);  // exact: NN = 3125*16
        const int* tp = tokens + node * BAG;
        float a[8];
#pragma unroll
        for (int j = 0; j < 8; j++) a[j] = 0.f;
        int c = 0;
#pragma unroll
        for (int t = 0; t < BAG; t++) {
            int tok = tp[t];  // group-uniform broadcast load
            c += (tok != PAD_IDX);
            v8s v = *(const v8s*)(table + (size_t)tok * EMB + sl * 8);
            acc8(a, v);
        }
        float inv = 1.0f / (float)(c > 0 ? c : 1);
        uint4 o;
        o.x = f2bf(a[0] * inv) | ((unsigned)f2bf(a[1] * inv) << 16);
        o.y = f2bf(a[2] * inv) | ((unsigned)f2bf(a[3] * inv) << 16);
        o.z = f2bf(a[4] * inv) | ((unsigned)f2bf(a[5] * inv) << 16);
        o.w = f2bf(a[6] * inv) | ((unsigned)f2bf(a[7] * inv) << 16);
        *(uint4*)(x0 + (size_t)node * EMB + sl * 8) = o;
        return;
    }
    int t = (b - EMVB) * 256 + threadIdx.x;
    if (t < NE8) {
        int4 s0 = *((const int4*)src + t * 2);
        int4 s1 = *((const int4*)src + t * 2 + 1);
        int4 d0 = *((const int4*)dst + t * 2);
        int4 d1 = *((const int4*)dst + t * 2 + 1);
        int p0 = atomicAdd(&cnt[d0.x], 1);
        int p1 = atomicAdd(&cnt[d0.y], 1);
        int p2 = atomicAdd(&cnt[d0.z], 1);
        int p3 = atomicAdd(&cnt[d0.w], 1);
        int p4 = atomicAdd(&cnt[d1.x], 1);
        int p5 = atomicAdd(&cnt[d1.y], 1);
        int p6 = atomicAdd(&cnt[d1.z], 1);
        int p7 = atomicAdd(&cnt[d1.w], 1);
        if (p0 < SLOTS) slots[(size_t)d0.x * SLOTS + p0] = s0.x;
        if (p1 < SLOTS) slots[(size_t)d0.y * SLOTS + p1] = s0.y;
        if (p2 < SLOTS) slots[(size_t)d0.z * SLOTS + p2] = s0.z;
        if (p3 < SLOTS) slots[(size_t)d0.w * SLOTS + p3] = s0.w;
        if (p4 < SLOTS) slots[(size_t)d1.x * SLOTS + p4] = s1.x;
        if (p5 < SLOTS) slots[(size_t)d1.y * SLOTS + p5] = s1.y;
        if (p6 < SLOTS) slots[(size_t)d1.z * SLOTS + p6] = s1.z;
        if (p7 < SLOTS) slots[(size_t)d1.w * SLOTS + p7] = s1.w;
    }
}

// ---------- neighbor mean aggregation (slot-CSR) ----------
// One wave/node; the node's <=64 indices are ONE 256B lane-parallel load, then
// broadcast via shfl: the gather loop has NO index loads -> pure MLP gathers.
__global__ __launch_bounds__(256) void k_aggr(const unsigned short* __restrict__ x,
                                              const int* __restrict__ cnt,
                                              const int* __restrict__ slots,
                                              unsigned short* __restrict__ aggr) {
    int node = blockIdx.x * 4 + (threadIdx.x >> 6);
    int lane = threadIdx.x & 63;
    if (node >= NN) return;
    int deg = cnt[node];
    int m = deg > SLOTS ? SLOTS : deg;
    int g = lane >> 4, sl = lane & 15;
    float a[8];
#pragma unroll
    for (int j = 0; j < 8; j++) a[j] = 0.f;
    int idx_l = slots[(size_t)node * SLOTS + ((lane < m) ? lane : 0)];
    int i = 0;
    for (; i + 8 <= m; i += 8) {  // 2 KB in flight, no index loads
        int t0 = __shfl(idx_l, i + g, 64);
        int t1 = __shfl(idx_l, i + 4 + g, 64);
        v8s v0 = *(const v8s*)(x + (size_t)t0 * HID + sl * 8);
        v8s v1 = *(const v8s*)(x + (size_t)t1 * HID + sl * 8);
        acc8(a, v0);
        acc8(a, v1);
    }
    for (; i + 4 <= m; i += 4) {
        int t0 = __shfl(idx_l, i + g, 64);
        v8s v0 = *(const v8s*)(x + (size_t)t0 * HID + sl * 8);
        acc8(a, v0);
    }
    int rem = m - i;  // 0..3
    if (rem > 0) {
        int t0 = __shfl(idx_l, (g < rem) ? i + g : i, 64);
        v8s v0 = *(const v8s*)(x + (size_t)t0 * HID + sl * 8);
        if (g < rem) acc8(a, v0);
    }
#pragma unroll
    for (int j = 0; j < 8; j++) {
        a[j] += __shfl_xor(a[j], 16, 64);
        a[j] += __shfl_xor(a[j], 32, 64);
    }
    float inv = 1.0f / (float)(deg > 0 ? deg : 1);
    if (g == 0) {
        uint4 o;
        o.x = f2bf(a[0] * inv) | ((unsigned)f2bf(a[1] * inv) << 16);
        o.y = f2bf(a[2] * inv) | ((unsigned)f2bf(a[3] * inv) << 16);
        o.z = f2bf(a[4] * inv) | ((unsigned)f2bf(a[5] * inv) << 16);
        o.w = f2bf(a[6] * inv) | ((unsigned)f2bf(a[7] * inv) << 16);
        *(uint4*)(aggr + (size_t)node * HID + sl * 8) = o;
    }
}

// ---------- shared MFMA K-loop for a 128-row tile ----------
__device__ __forceinline__ void sage_kloop(int row0, const unsigned short* __restrict__ xa,
                                           const unsigned short* __restrict__ xr,
                                           const unsigned short* __restrict__ wl,
                                           const unsigned short* __restrict__ wr,
                                           unsigned short* As, unsigned short* Bs,
                                           v4f acc[2][8]) {
    int tid = threadIdx.x;
    int wave = tid >> 6, lane = tid & 63;
    int q = lane >> 4, l16 = lane & 15;
    for (int kc = 0; kc < 8; kc++) {
        const unsigned short* Ag = (kc < 4) ? xa : xr;
        const unsigned short* Bg = (kc < 4) ? wl : wr;
        int koff = (kc & 3) * 32;
#pragma unroll
        for (int it = 0; it < 2; it++) {
            int seg = tid + it * 256;  // 128 rows x 4 segments of 8 bf16
            int r = seg >> 2, sg = seg & 3;
            int gr = row0 + r;
            if (gr > NN - 1) gr = NN - 1;
            v8s a = *(const v8s*)(Ag + (size_t)gr * HID + koff + sg * 8);
            *(v8s*)(As + r * 32 + sg * 8) = a;
            v8s b = *(const v8s*)(Bg + (size_t)r * HID + koff + sg * 8);
            *(v8s*)(Bs + r * 32 + sg * 8) = b;
        }
        __syncthreads();
        v8s a0 = *(const v8s*)(As + (wave * 32 + l16) * 32 + q * 8);
        v8s a1 = *(const v8s*)(As + (wave * 32 + 16 + l16) * 32 + q * 8);
#pragma unroll
        for (int nt = 0; nt < 8; nt++) {
            v8s b = *(const v8s*)(Bs + (nt * 16 + l16) * 32 + q * 8);
            acc[0][nt] = __builtin_amdgcn_mfma_f32_16x16x32_bf16(a0, b, acc[0][nt], 0, 0, 0);
            acc[1][nt] = __builtin_amdgcn_mfma_f32_16x16x32_bf16(a1, b, acc[1][nt], 0, 0, 0);
        }
        __syncthreads();
    }
}

// ---------- SAGE layer 1: relu(aggr@wl^T + b + x@wr^T) -> global x1 ----------
__global__ __launch_bounds__(256) void k_sage(const unsigned short* __restrict__ xa,
                                              const unsigned short* __restrict__ xr,
                                              const unsigned short* __restrict__ wl,
                                              const unsigned short* __restrict__ wr,
                                              const float* __restrict__ bias,
                                              unsigned short* __restrict__ out) {
    __shared__ unsigned short As[128 * 32];
    __shared__ unsigned short Bs[128 * 32];
    int row0 = blockIdx.x * 128;
    v4f acc[2][8];
#pragma unroll
    for (int m = 0; m < 2; m++)
#pragma unroll
        for (int n = 0; n < 8; n++) acc[m][n] = (v4f){0.f, 0.f, 0.f, 0.f};
    sage_kloop(row0, xa, xr, wl, wr, As, Bs, acc);
    int tid = threadIdx.x;
    int wave = tid >> 6, lane = tid & 63;
    int q = lane >> 4, l16 = lane & 15;
#pragma unroll
    for (int nt = 0; nt < 8; nt++) {
        int col = nt * 16 + l16;
        float bv = bias[col];
#pragma unroll
        for (int mt = 0; mt < 2; mt++) {
#pragma unroll
            for (int r = 0; r < 4; r++) {
                int row = row0 + wave * 32 + mt * 16 + q * 4 + r;
                if (row < NN) {
                    float v = acc[mt][nt][r] + bv;
                    v = v > 0.f ? v : 0.f;
                    out[(size_t)row * HID + col] = f2bf(v);
                }
            }
        }
    }
}

// ---------- SAGE layer 2 fused with global mean pool ----------
// Activations go to a 32KB LDS tile (no x2 global round-trip); then the block
// run-length-pools its own 128 sorted rows (same chunking/order as old k_pool).
__global__ __launch_bounds__(256) void k_sagepool(const unsigned short* __restrict__ xa,
                                                  const unsigned short* __restrict__ xr,
                                                  const unsigned short* __restrict__ wl,
                                                  const unsigned short* __restrict__ wr,
                                                  const float* __restrict__ bias,
                                                  const int* __restrict__ batch,
                                                  float* __restrict__ gsum,
                                                  float* __restrict__ gcnt) {
    __shared__ unsigned short smem[128 * 128];  // 32KB; first 16KB doubles as As|Bs
    unsigned short* As = smem;
    unsigned short* Bs = smem + 128 * 32;
    int row0 = blockIdx.x * 128;
    v4f acc[2][8];
#pragma unroll
    for (int m = 0; m < 2; m++)
#pragma unroll
        for (int n = 0; n < 8; n++) acc[m][n] = (v4f){0.f, 0.f, 0.f, 0.f};
    sage_kloop(row0, xa, xr, wl, wr, As, Bs, acc);
    // K-loop ends with __syncthreads(); As/Bs dead -> overlay the x2 tile on smem
    int tid = threadIdx.x;
    int wave = tid >> 6, lane = tid & 63;
    int q = lane >> 4, l16 = lane & 15;
#pragma unroll
    for (int nt = 0; nt < 8; nt++) {
        int col = nt * 16 + l16;
        float bv = bias[col];
#pragma unroll
        for (int mt = 0; mt < 2; mt++) {
#pragma unroll
            for (int r = 0; r < 4; r++) {
                int rl = wave * 32 + mt * 16 + q * 4 + r;  // local row 0..127
                float v = acc[mt][nt][r] + bv;
                v = v > 0.f ? v : 0.f;
                smem[rl * 128 + col] = f2bf(v);
            }
        }
    }
    __syncthreads();
    // pool: thread col over this tile's rows (identical order to old k_pool chunk)
    if (tid < 128) {
        int col = tid;
        int end = NN - row0;
        if (end > 128) end = 128;
        int cur = batch[row0];
        float acc_p = 0.f;
        int c = 0;
        for (int i = 0; i < end; i++) {
            int b = batch[row0 + i];  // uniform across block
            if (b != cur) {
                atomicAdd(&gsum[cur * HID + col], acc_p);
                if (col == 0) atomicAdd(&gcnt[cur], (float)c);
                acc_p = 0.f;
                c = 0;
                cur = b;
            }
            acc_p += __uint_as_float(((unsigned)smem[i * 128 + col]) << 16);
            c++;
        }
        atomicAdd(&gsum[cur * HID + col], acc_p);
        if (col == 0) atomicAdd(&gcnt[cur], (float)c);
    }
}

// ---------- final classifier ----------
__global__ __launch_bounds__(128) void k_final(const float* __restrict__ gsum,
                                               const float* __restrict__ gcnt,
                                               const float* __restrict__ w_out,
                                               const float* __restrict__ b_out,
                                               float* __restrict__ out) {
    __shared__ float mean[HID];
    int g = blockIdx.x, tid = threadIdx.x;
    mean[tid] = gsum[g * HID + tid] / fmaxf(gcnt[g], 1.0f);
    __syncthreads();
    if (tid < NC) {
        float s = b_out[tid];
#pragma unroll 16
        for (int d = 0; d < HID; d++) s += mean[d] * w_out[tid * HID + d];
        out[g * NC + tid] = s;
    }
}

extern "C" void kernel_launch(void* const* d_in, const int* in_sizes, int n_in,
                              void* d_out, int out_size, void* d_ws, size_t ws_size,
                              hipStream_t stream) {
    const int* x_tokens = (const int*)d_in[0];
    const int* edge = (const int*)d_in[1];
    const int* batch = (const int*)d_in[2];
    const float* emb_table = (const float*)d_in[3];
    const float* w1l = (const float*)d_in[4];
    const float* b1 = (const float*)d_in[5];
    const float* w1r = (const float*)d_in[6];
    const float* w2l = (const float*)d_in[7];
    const float* b2 = (const float*)d_in[8];
    const float* w2r = (const float*)d_in[9];
    const float* w_out = (const float*)d_in[10];
    const float* b_out = (const float*)d_in[11];
    float* out = (float*)d_out;

    char* ws = (char*)d_ws;
    size_t off = 0;
    auto alloc = [&](size_t bytes) {
        void* p = ws + off;
        off += (bytes + 255) & ~(size_t)255;
        return p;
    };
    int* cnt = (int*)alloc(NN * 4);
    int* slots = (int*)alloc((size_t)NN * SLOTS * 4);  // fixed-width CSR, 12.8 MB
    unsigned short* wbf = (unsigned short*)alloc(4 * HID * EMB * 2);
    float* gsum = (float*)alloc(NG * HID * 4);
    float* gcnt = (float*)alloc(NG * 4);
    unsigned short* x0 = (unsigned short*)alloc((size_t)NN * EMB * 2);
    unsigned short* x1 = (unsigned short*)alloc((size_t)NN * HID * 2);
    unsigned short* aggrb = (unsigned short*)alloc((size_t)NN * HID * 2);
    unsigned short* table_bf = x1;  // x1 dead until sage1 writes it; reuse

    const int* srcp = edge;
    const int* dstp = edge + NE;

    k_conv<<<(TPAIRS + WPAIRS + 255) / 256, 256, 0, stream>>>(
        emb_table, table_bf, w1l, w1r, w2l, w2r, wbf, cnt, gsum, gcnt);
    k_scatem<<<EMVB + SC8BLK, 256, 0, stream>>>(srcp, dstp, cnt, slots, x_tokens,
                                                table_bf, x0);
    k_aggr<<<(NN + 3) / 4, 256, 0, stream>>>(x0, cnt, slots, aggrb);
    k_sage<<<NTILES, 256, 0, stream>>>(aggrb, x0, wbf, wbf + 16384, b1, x1);
    k_aggr<<<(NN + 3) / 4, 256, 0, stream>>>(x1, cnt, slots, aggrb);
    k_sagepool<<<NTILES, 256, 0, stream>>>(aggrb, x1, wbf + 32768, wbf + 49152, b2,
                                           batch, gsum, gcnt);
    k_final<<<NG, 128, 0, stream>>>(gsum, gcnt, w_out, b_out, out);
}